// Round 1
// baseline (15589.532 us; speedup 1.0000x reference)
//
#include <hip/hip_runtime.h>

// Problem constants (fixed by reference: N=32768, K=8192, D=256, fp32 in, int32 out)
constexpr int D_DIM   = 256;
constexpr int N_ROWS  = 32768;
constexpr int K_CODES = 8192;
constexpr int BM      = 64;    // rows per block
constexpr int BN      = 128;   // codes per k-tile
constexpr int CHUNK   = 16;    // d-depth per staged e-chunk
constexpr int NCHUNK  = D_DIM / CHUNK;  // 16
constexpr int NTILES  = K_CODES / BN;   // 64

// ---------------------------------------------------------------------------
// Prologue: e_sq[k] (k<8192) and x_sq[n] into ws. One wave per vector:
// lane reads float4 (64 lanes x 16B = full 1KB row), shfl-tree reduce.
// ---------------------------------------------------------------------------
__global__ void sumsq_kernel(const float* __restrict__ X, const float* __restrict__ E,
                             float* __restrict__ ws) {
    const int gw   = (int)((blockIdx.x * blockDim.x + threadIdx.x) >> 6);
    const int lane = threadIdx.x & 63;
    const float* base = (gw < K_CODES) ? (E + (size_t)gw * D_DIM)
                                       : (X + (size_t)(gw - K_CODES) * D_DIM);
    const float4 v = ((const float4*)base)[lane];
    float s = v.x * v.x + v.y * v.y + v.z * v.z + v.w * v.w;
#pragma unroll
    for (int off = 32; off; off >>= 1) s += __shfl_down(s, off, 64);
    if (lane == 0) ws[gw] = s;
}

// ---------------------------------------------------------------------------
// Main: fused distance GEMM + row argmin.
// Block: 64 rows x (loop over all 8192 codes in 128-wide tiles).
// Thread (cth = tid&15, rth = tid>>4): rows {4*rth..+3} x codes {8*cth..+7}.
// x-tile resident in LDS (XOR-swizzled, stride 256); e staged in 16-d chunks,
// double-buffered. Epilogue mimics reference rounding:
//   d = fma(-2, c, fl(x_sq + e_sq))   (2c exact => identical to ref op order)
// Argmin: strict < ascending k (first-occurrence); cross-lane reduce prefers
// lower index on exact tie.
// ---------------------------------------------------------------------------
__global__ __launch_bounds__(256, 2)
void vq_argmin_kernel(const float* __restrict__ X, const float* __restrict__ E,
                      const float* __restrict__ ws, int* __restrict__ out) {
    __shared__ float xs[BM * D_DIM];        // 64 KB, swizzled: [row][d ^ ((row>>2&7)<<2)]
    __shared__ float es[2][BN * CHUNK];     // 2 x 8 KB, swizzled: [code][dd ^ ((code>>3&3)<<2)]

    const int tid  = threadIdx.x;
    const int row0 = blockIdx.x * BM;
    const int cth  = tid & 15;
    const int rth  = tid >> 4;

    // ---- stage x tile (coalesced: 256 lanes = one full row per step) ----
    {
        const int d = tid;
#pragma unroll 4
        for (int i = 0; i < BM; ++i) {
            xs[i * D_DIM + (d ^ (((i >> 2) & 7) << 2))] = X[(size_t)(row0 + i) * D_DIM + d];
        }
    }

    float xsq[4];
#pragma unroll
    for (int i = 0; i < 4; ++i) xsq[i] = ws[K_CODES + row0 + 4 * rth + i];

    float best[4];
    int   bidx[4];
#pragma unroll
    for (int i = 0; i < 4; ++i) { best[i] = 3.402823e38f; bidx[i] = 0; }

    // e-staging lanes: q = d-quad, cp = code (two codes per thread: cp, cp+64)
    const int q   = tid & 3;
    const int cp  = tid >> 2;
    const int se0 = ((cp >> 3) & 3) << 2;   // store swizzle (same for cp and cp+64)
    const int sev = (cth & 3) << 2;         // read swizzle for codes 8*cth+j (code>>3 == cth)
    const int sx  = (rth & 7) << 2;         // x read swizzle ( (4*rth+i)>>2 == rth )

    for (int kt = 0; kt < NTILES; ++kt) {
        const int code0 = kt * BN;

        float esq[8];
#pragma unroll
        for (int j = 0; j < 8; ++j) esq[j] = ws[code0 + 8 * cth + j];

        // stage chunk 0
        {
            const float4 a = *(const float4*)&E[(size_t)(code0 + cp) * D_DIM + 4 * q];
            const float4 b = *(const float4*)&E[(size_t)(code0 + cp + 64) * D_DIM + 4 * q];
            *(float4*)&es[0][cp * CHUNK + ((4 * q) ^ se0)]        = a;
            *(float4*)&es[0][(cp + 64) * CHUNK + ((4 * q) ^ se0)] = b;
        }

        float acc[4][8];
#pragma unroll
        for (int i = 0; i < 4; ++i)
#pragma unroll
            for (int j = 0; j < 8; ++j) acc[i][j] = 0.0f;

        __syncthreads();   // xs (first tile) + chunk0 visible

#pragma unroll 2
        for (int ch = 0; ch < NCHUNK; ++ch) {
            const int  pb      = ch & 1;
            const bool hasNext = (ch + 1 < NCHUNK);
            float4 n0, n1;
            if (hasNext) {
                const int d0n = (ch + 1) * CHUNK + 4 * q;
                n0 = *(const float4*)&E[(size_t)(code0 + cp) * D_DIM + d0n];
                n1 = *(const float4*)&E[(size_t)(code0 + cp + 64) * D_DIM + d0n];
            }
#pragma unroll
            for (int s4 = 0; s4 < CHUNK / 4; ++s4) {
                const int dg = ch * CHUNK + 4 * s4;
                float4 xv[4];
#pragma unroll
                for (int i = 0; i < 4; ++i) {
                    const int row = 4 * rth + i;
                    xv[i] = *(const float4*)&xs[row * D_DIM + (dg ^ sx)];
                }
                float4 ev[8];
#pragma unroll
                for (int j = 0; j < 8; ++j) {
                    const int code = 8 * cth + j;
                    ev[j] = *(const float4*)&es[pb][code * CHUNK + ((4 * s4) ^ sev)];
                }
#pragma unroll
                for (int i = 0; i < 4; ++i) {
#pragma unroll
                    for (int j = 0; j < 8; ++j) {
                        acc[i][j] = fmaf(xv[i].x, ev[j].x, acc[i][j]);
                        acc[i][j] = fmaf(xv[i].y, ev[j].y, acc[i][j]);
                        acc[i][j] = fmaf(xv[i].z, ev[j].z, acc[i][j]);
                        acc[i][j] = fmaf(xv[i].w, ev[j].w, acc[i][j]);
                    }
                }
            }
            if (hasNext) {
                *(float4*)&es[pb ^ 1][cp * CHUNK + ((4 * q) ^ se0)]        = n0;
                *(float4*)&es[pb ^ 1][(cp + 64) * CHUNK + ((4 * q) ^ se0)] = n1;
            }
            __syncthreads();
        }

        // ---- epilogue: distances + running argmin (ascending k, strict <) ----
#pragma unroll
        for (int j = 0; j < 8; ++j) {
            const int code = code0 + 8 * cth + j;
#pragma unroll
            for (int i = 0; i < 4; ++i) {
                const float t  = xsq[i] + esq[j];              // fl(x_sq + e_sq), as ref
                const float dv = fmaf(-2.0f, acc[i][j], t);    // fl(t - 2c), 2c exact
                if (dv < best[i]) { best[i] = dv; bidx[i] = code; }
            }
        }
    }

    // ---- cross-lane reduce over the 16 code-threads (lanes grouped by rth) ----
#pragma unroll
    for (int off = 8; off; off >>= 1) {
#pragma unroll
        for (int i = 0; i < 4; ++i) {
            const float ov = __shfl_down(best[i], off, 16);
            const int   oi = __shfl_down(bidx[i], off, 16);
            if (ov < best[i] || (ov == best[i] && oi < bidx[i])) { best[i] = ov; bidx[i] = oi; }
        }
    }
    if (cth == 0) {
#pragma unroll
        for (int i = 0; i < 4; ++i) out[row0 + 4 * rth + i] = bidx[i];
    }
}

// ---------------------------------------------------------------------------
extern "C" void kernel_launch(void* const* d_in, const int* in_sizes, int n_in,
                              void* d_out, int out_size, void* d_ws, size_t ws_size,
                              hipStream_t stream) {
    const float* X  = (const float*)d_in[0];   // inputs   [32768, 256]
    const float* E  = (const float*)d_in[1];   // codebook [8192, 256]
    float*       ws = (float*)d_ws;            // [0,8192): e_sq, [8192,40960): x_sq
    int*         out = (int*)d_out;            // [32768] int32 indices

    // 40960 vectors, 4 waves/block -> 10240 blocks
    sumsq_kernel<<<dim3((K_CODES + N_ROWS) / 4), dim3(256), 0, stream>>>(X, E, ws);
    vq_argmin_kernel<<<dim3(N_ROWS / BM), dim3(256), 0, stream>>>(X, E, ws, out);
}

// Round 2
// 8087.787 us; speedup vs baseline: 1.9275x; 1.9275x over previous
//
#include <hip/hip_runtime.h>

// Problem constants (fixed by reference: N=32768, K=8192, D=256, fp32 in, int32 out)
constexpr int D_DIM   = 256;
constexpr int N_ROWS  = 32768;
constexpr int K_CODES = 8192;
constexpr int BM      = 64;     // rows per block; lane <-> row
constexpr int XS_STRIDE = 260;  // 256 + 4 pad: byte stride 1040 ≡ 16 mod 128 -> 2-way (free) b128 access
constexpr int CTILE   = 16;     // codes per tile (acc registers; keeps unrolled body ~8 KB I$)
constexpr int DC      = 64;     // d-chunk floats held in VGPRs per tile pass
constexpr int NTILES  = K_CODES / CTILE;  // 512

// ---------------------------------------------------------------------------
// Prologue: e_sq[k] (k<8192) then x_sq[n] into ws. One wave per vector.
// ---------------------------------------------------------------------------
__global__ void sumsq_kernel(const float* __restrict__ X, const float* __restrict__ E,
                             float* __restrict__ ws) {
    const int gw   = (int)((blockIdx.x * blockDim.x + threadIdx.x) >> 6);
    const int lane = threadIdx.x & 63;
    const float* base = (gw < K_CODES) ? (E + (size_t)gw * D_DIM)
                                       : (X + (size_t)(gw - K_CODES) * D_DIM);
    const float4 v = ((const float4*)base)[lane];
    float s = v.x * v.x + v.y * v.y + v.z * v.z + v.w * v.w;
#pragma unroll
    for (int off = 32; off; off >>= 1) s += __shfl_down(s, off, 64);
    if (lane == 0) ws[gw] = s;
}

// ---------------------------------------------------------------------------
// Main: lane <-> row; e broadcast through SGPRs (uniform address -> s_load),
// inner op is v_fma_f32(vgpr_x, sgpr_e, acc). x-tile resident in LDS, read
// 0.25 B per FMA (overlapped). No barriers in the main loop; the 4 waves of
// a block split the code tiles round-robin and combine argmins at the end.
// Arithmetic per (row, code) is bit-identical to the verified round-1 path:
// acc = fma-chain over d ascending; dist = fma(-2, acc, fl(x_sq + e_sq)).
// ---------------------------------------------------------------------------
__global__ __launch_bounds__(256, 1)
void vq_argmin_kernel(const float* __restrict__ X, const float* __restrict__ E,
                      const float* __restrict__ ws, int* __restrict__ out) {
    __shared__ float xs[BM * XS_STRIDE];   // 66,560 B
    __shared__ float rbest[4 * BM];
    __shared__ int   ridx[4 * BM];

    const int tid  = threadIdx.x;
    const int lane = tid & 63;
    const int wv   = tid >> 6;             // wave id 0..3
    const int row0 = blockIdx.x * BM;

    // ---- stage 64 rows x 256 floats, fully coalesced float4 ----
#pragma unroll
    for (int i = 0; i < 16; ++i) {
        const int f = tid + 256 * i;       // float4 index 0..4095
        const int r = f >> 6;              // row 0..63
        const int p = f & 63;              // float4 position in row
        const float4 v = *(const float4*)&X[(size_t)(row0 + r) * D_DIM + 4 * p];
        *(float4*)&xs[r * XS_STRIDE + 4 * p] = v;
    }
    __syncthreads();

    const float xsq = ws[K_CODES + row0 + lane];
    float best = 3.402823e38f;
    int   bidx = 0;

    // wave wv handles tiles wv, wv+4, wv+8, ... (codes ascending within wave)
#pragma unroll 1
    for (int t = wv; t < NTILES; t += 4) {
        const int k0 = t * CTILE;

        float acc[CTILE];
#pragma unroll
        for (int k = 0; k < CTILE; ++k) acc[k] = 0.0f;

#pragma unroll 1
        for (int dc = 0; dc < D_DIM / DC; ++dc) {      // 4 d-chunks of 64
            // lane's own row chunk: 16 x ds_read_b128, reused by 16 codes
            float4 xv[DC / 4];
#pragma unroll
            for (int j = 0; j < DC / 4; ++j)
                xv[j] = *(const float4*)&xs[lane * XS_STRIDE + dc * DC + 4 * j];

#pragma unroll
            for (int k = 0; k < CTILE; ++k) {
                const float* __restrict__ ek = &E[(size_t)(k0 + k) * D_DIM + dc * DC];
                float a = acc[k];
#pragma unroll
                for (int j = 0; j < DC / 4; ++j) {
                    // ek[*] is wave-uniform -> SGPR operand of v_fma_f32
                    a = fmaf(xv[j].x, ek[4 * j + 0], a);
                    a = fmaf(xv[j].y, ek[4 * j + 1], a);
                    a = fmaf(xv[j].z, ek[4 * j + 2], a);
                    a = fmaf(xv[j].w, ek[4 * j + 3], a);
                }
                acc[k] = a;
            }
        }

        // ---- distances + running argmin (codes ascending; strict < = first) ----
#pragma unroll
        for (int k = 0; k < CTILE; ++k) {
            const float t2 = xsq + ws[k0 + k];          // fl(x_sq + e_sq), as ref
            const float dv = fmaf(-2.0f, acc[k], t2);   // fl(t - 2c), 2c exact
            if (dv < best) { best = dv; bidx = k0 + k; }
        }
    }

    // ---- combine the 4 waves' per-row results ----
    rbest[wv * BM + lane] = best;
    ridx [wv * BM + lane] = bidx;
    __syncthreads();
    if (tid < BM) {
        float b  = rbest[tid];
        int   bi = ridx[tid];
#pragma unroll
        for (int w = 1; w < 4; ++w) {
            const float ov = rbest[w * BM + tid];
            const int   oi = ridx [w * BM + tid];
            if (ov < b || (ov == b && oi < bi)) { b = ov; bi = oi; }
        }
        out[row0 + tid] = bi;
    }
}

// ---------------------------------------------------------------------------
extern "C" void kernel_launch(void* const* d_in, const int* in_sizes, int n_in,
                              void* d_out, int out_size, void* d_ws, size_t ws_size,
                              hipStream_t stream) {
    const float* X  = (const float*)d_in[0];   // inputs   [32768, 256]
    const float* E  = (const float*)d_in[1];   // codebook [8192, 256]
    float*       ws = (float*)d_ws;            // [0,8192): e_sq, [8192,40960): x_sq
    int*         out = (int*)d_out;            // [32768] int32 indices

    sumsq_kernel<<<dim3((K_CODES + N_ROWS) / 4), dim3(256), 0, stream>>>(X, E, ws);
    vq_argmin_kernel<<<dim3(N_ROWS / BM), dim3(256), 0, stream>>>(X, E, ws, out);
}

// Round 4
// 640.048 us; speedup vs baseline: 24.3568x; 12.6362x over previous
//
#include <hip/hip_runtime.h>

// N=32768 rows, K=8192 codes, D=256, fp32 in, int32 out.
constexpr int D_DIM   = 256;
constexpr int N_ROWS  = 32768;
constexpr int K_CODES = 8192;
constexpr int BM      = 128;   // rows per block
constexpr int BN      = 128;   // codes per tile
constexpr int BK      = 64;    // d per staged chunk
constexpr int STRIP   = 2048;  // codes swept per block (4 strips)
constexpr int NSTRIP  = K_CODES / STRIP;   // 4
constexpr int NCT     = STRIP / BN;        // 16 code-tiles per strip

typedef _Float16 f16x8  __attribute__((ext_vector_type(8)));   // MFMA operand type
typedef __fp16   fp16x2 __attribute__((ext_vector_type(2)));   // cvt_pkrtz result type
typedef float    f32x16 __attribute__((ext_vector_type(16)));

#define MFMA32(a, b, c) __builtin_amdgcn_mfma_f32_32x32x16_f16(a, b, c, 0, 0, 0)

// Split one granule (8 fp32) into fp16 hi (pkrtz) + fp16 lo (residual).
__device__ __forceinline__ void cvt_granule(const float4 a, const float4 b,
                                            uint4& hi, uint4& lo) {
    fp16x2 h0 = __builtin_amdgcn_cvt_pkrtz(a.x, a.y);
    fp16x2 h1 = __builtin_amdgcn_cvt_pkrtz(a.z, a.w);
    fp16x2 h2 = __builtin_amdgcn_cvt_pkrtz(b.x, b.y);
    fp16x2 h3 = __builtin_amdgcn_cvt_pkrtz(b.z, b.w);
    fp16x2 l0 = __builtin_amdgcn_cvt_pkrtz(a.x - (float)h0.x, a.y - (float)h0.y);
    fp16x2 l1 = __builtin_amdgcn_cvt_pkrtz(a.z - (float)h1.x, a.w - (float)h1.y);
    fp16x2 l2 = __builtin_amdgcn_cvt_pkrtz(b.x - (float)h2.x, b.y - (float)h2.y);
    fp16x2 l3 = __builtin_amdgcn_cvt_pkrtz(b.z - (float)h3.x, b.w - (float)h3.y);
    hi = make_uint4(__builtin_bit_cast(unsigned, h0), __builtin_bit_cast(unsigned, h1),
                    __builtin_bit_cast(unsigned, h2), __builtin_bit_cast(unsigned, h3));
    lo = make_uint4(__builtin_bit_cast(unsigned, l0), __builtin_bit_cast(unsigned, l1),
                    __builtin_bit_cast(unsigned, l2), __builtin_bit_cast(unsigned, l3));
}

// ---------------------------------------------------------------------------
// Prologue: esq_biased[k] = ||e_k||^2 + 1024 (bias keeps all compare-values
// positive => u64 bit-packing is order-preserving); init packed[] to max.
// ---------------------------------------------------------------------------
__global__ void prologue_kernel(const float* __restrict__ E, float* __restrict__ esqb,
                                unsigned long long* __restrict__ packed) {
    const int t = blockIdx.x * 256 + threadIdx.x;
    if (t < N_ROWS) packed[t] = ~0ull;
    const int gw   = t >> 6;          // 0..8191 (grid = 2048 blocks)
    const int lane = t & 63;
    const float4 v = ((const float4*)(E + (size_t)gw * D_DIM))[lane];
    float s = v.x * v.x + v.y * v.y + v.z * v.z + v.w * v.w;
#pragma unroll
    for (int off = 32; off; off >>= 1) s += __shfl_down(s, off, 64);
    if (lane == 0) esqb[gw] = s + 1024.0f;
}

// ---------------------------------------------------------------------------
// Main: split-fp16 MFMA distance GEMM + fused argmin.
// Wave (wr,wc) of 2x2 owns a 64x64 sub-tile = 2x2 MFMAs of 32x32x16 f16.
// Per K-step: 8 ds_read_b128 (xh,xl,eh,el frags), 12 MFMA (3 products).
// Compare value: esq + 1024 - 2c  (row-constant xsq dropped: same argmin).
// ---------------------------------------------------------------------------
__global__ __launch_bounds__(256, 2)
void vq_mfma_kernel(const float* __restrict__ X, const float* __restrict__ E,
                    const float* __restrict__ esqb,
                    unsigned long long* __restrict__ packed) {
    __shared__ uint4 sXh[BM * 8], sXl[BM * 8];   // 16 KB each (granule = 8 f16)
    __shared__ uint4 sEh[BN * 8], sEl[BN * 8];   // 16 KB each
    __shared__ float sEsq[STRIP];                // 8 KB

    const int tid  = threadIdx.x;
    const int lane = tid & 63;
    const int wv   = tid >> 6;
    const int wr   = wv >> 1, wc = wv & 1;
    const int l31  = lane & 31;
    const int lh   = lane >> 5;
    const int row0 = blockIdx.x * BM;
    const int cs0  = blockIdx.y * STRIP;

    // stage biased e_sq for this strip
#pragma unroll
    for (int i = 0; i < STRIP / 256; ++i)
        sEsq[tid + 256 * i] = esqb[cs0 + tid + 256 * i];

    const int sr = tid >> 3;     // staging sub-row 0..31
    const int sg = tid & 7;      // staging granule 0..7

    float best[2][16];
    int   bidx[2][16];
#pragma unroll
    for (int ti = 0; ti < 2; ++ti)
#pragma unroll
        for (int r = 0; r < 16; ++r) { best[ti][r] = 3.0e38f; bidx[ti][r] = 0; }

    f32x16 acc[2][2];

#pragma unroll 1
    for (int ct = 0; ct < NCT; ++ct) {
#pragma unroll
        for (int ti = 0; ti < 2; ++ti)
#pragma unroll
            for (int tj = 0; tj < 2; ++tj)
#pragma unroll
                for (int i = 0; i < 16; ++i) acc[ti][tj][i] = 0.0f;

#pragma unroll 1
        for (int dc = 0; dc < D_DIM / BK; ++dc) {
            __syncthreads();   // previous chunk's reads complete
            // ---- stage X chunk [128 rows][64 d] split hi/lo ----
#pragma unroll
            for (int i = 0; i < 4; ++i) {
                const int r = 32 * i + sr;
                const float* p = X + (size_t)(row0 + r) * D_DIM + dc * BK + sg * 8;
                const float4 a = *(const float4*)p;
                const float4 b = *(const float4*)(p + 4);
                uint4 hi, lo; cvt_granule(a, b, hi, lo);
                const int o = r * 8 + (sg ^ (r & 7));
                sXh[o] = hi; sXl[o] = lo;
            }
            // ---- stage E chunk [128 codes][64 d] split hi/lo ----
#pragma unroll
            for (int i = 0; i < 4; ++i) {
                const int r = 32 * i + sr;
                const float* p = E + (size_t)(cs0 + ct * BN + r) * D_DIM + dc * BK + sg * 8;
                const float4 a = *(const float4*)p;
                const float4 b = *(const float4*)(p + 4);
                uint4 hi, lo; cvt_granule(a, b, hi, lo);
                const int o = r * 8 + (sg ^ (r & 7));
                sEh[o] = hi; sEl[o] = lo;
            }
            __syncthreads();

            // ---- 4 K-steps of 16 ----
#pragma unroll
            for (int s = 0; s < 4; ++s) {
                const int gi = s * 2 + lh;
                f16x8 axh[2], axl[2], beh[2], bel[2];
#pragma unroll
                for (int ti = 0; ti < 2; ++ti) {
                    const int r = wr * 64 + ti * 32 + l31;
                    const int o = r * 8 + (gi ^ (r & 7));
                    axh[ti] = __builtin_bit_cast(f16x8, sXh[o]);
                    axl[ti] = __builtin_bit_cast(f16x8, sXl[o]);
                }
#pragma unroll
                for (int tj = 0; tj < 2; ++tj) {
                    const int c = wc * 64 + tj * 32 + l31;
                    const int o = c * 8 + (gi ^ (c & 7));
                    beh[tj] = __builtin_bit_cast(f16x8, sEh[o]);
                    bel[tj] = __builtin_bit_cast(f16x8, sEl[o]);
                }
#pragma unroll
                for (int ti = 0; ti < 2; ++ti)
#pragma unroll
                    for (int tj = 0; tj < 2; ++tj) {
                        acc[ti][tj] = MFMA32(axl[ti], beh[tj], acc[ti][tj]);  // small terms first
                        acc[ti][tj] = MFMA32(axh[ti], bel[tj], acc[ti][tj]);
                        acc[ti][tj] = MFMA32(axh[ti], beh[tj], acc[ti][tj]);
                    }
            }
        }

        // ---- epilogue: compare-value + running argmin (codes ascending) ----
#pragma unroll
        for (int tj = 0; tj < 2; ++tj) {
            const int cloc = ct * BN + wc * 64 + tj * 32 + l31;
            const float eb = sEsq[cloc];         // esq + 1024
            const int  code = cs0 + cloc;
#pragma unroll
            for (int ti = 0; ti < 2; ++ti)
#pragma unroll
                for (int r = 0; r < 16; ++r) {
                    const float dv = fmaf(-2.0f, acc[ti][tj][r], eb);
                    if (dv < best[ti][r]) { best[ti][r] = dv; bidx[ti][r] = code; }
                }
        }
    }

    // ---- butterfly reduce across the 32 lanes sharing each row set ----
#pragma unroll
    for (int ti = 0; ti < 2; ++ti)
#pragma unroll
        for (int r = 0; r < 16; ++r) {
            float b = best[ti][r]; int bi = bidx[ti][r];
#pragma unroll
            for (int m = 16; m >= 1; m >>= 1) {
                const float ov = __shfl_xor(b, m, 32);
                const int   oi = __shfl_xor(bi, m, 32);
                if (ov < b || (ov == b && oi < bi)) { b = ov; bi = oi; }
            }
            if (l31 == 0) {
                const int row = row0 + wr * 64 + ti * 32 + (r & 3) + 8 * (r >> 2) + 4 * lh;
                const unsigned long long p =
                    ((unsigned long long)__float_as_uint(b) << 32) | (unsigned)bi;
                atomicMin(&packed[row], p);   // positive floats: bit order = value order
            }
        }
}

// ---------------------------------------------------------------------------
__global__ void finish_kernel(const unsigned long long* __restrict__ packed,
                              int* __restrict__ out) {
    const int i = blockIdx.x * 256 + threadIdx.x;
    out[i] = (int)(unsigned)(packed[i] & 0xffffffffull);
}

// ---------------------------------------------------------------------------
extern "C" void kernel_launch(void* const* d_in, const int* in_sizes, int n_in,
                              void* d_out, int out_size, void* d_ws, size_t ws_size,
                              hipStream_t stream) {
    const float* X = (const float*)d_in[0];    // [32768, 256]
    const float* E = (const float*)d_in[1];    // [8192, 256]
    float* esqb = (float*)d_ws;                                        // 32 KB
    unsigned long long* packed = (unsigned long long*)((char*)d_ws + K_CODES * 4); // 256 KB
    int* out = (int*)d_out;

    prologue_kernel<<<dim3(K_CODES * 64 / 256), dim3(256), 0, stream>>>(E, esqb, packed);
    vq_mfma_kernel<<<dim3(N_ROWS / BM, NSTRIP), dim3(256), 0, stream>>>(X, E, esqb, packed);
    finish_kernel<<<dim3(N_ROWS / 256), dim3(256), 0, stream>>>(packed, out);
}

// Round 5
// 470.222 us; speedup vs baseline: 33.1536x; 1.3612x over previous
//
#include <hip/hip_runtime.h>

// N=32768 rows, K=8192 codes, D=256, fp32 in, int32 out.
constexpr int D_DIM   = 256;
constexpr int N_ROWS  = 32768;
constexpr int K_CODES = 8192;

// ---- fast path (pre-converted, blocked layout) ----
constexpr int BM     = 128;             // rows per block
constexpr int BN     = 256;             // codes per tile
constexpr int BK     = 32;              // d per staged chunk
constexpr int STRIP  = 4096;            // codes per block (2 strips)
constexpr int NSTRIP = K_CODES / STRIP; // 2
constexpr int NCT    = STRIP / BN;      // 16
constexpr int NDC    = D_DIM / BK;      // 8

typedef _Float16 f16x8  __attribute__((ext_vector_type(8)));
typedef __fp16   fp16x2 __attribute__((ext_vector_type(2)));
typedef float    f32x16 __attribute__((ext_vector_type(16)));

#define MFMA32(a, b, c) __builtin_amdgcn_mfma_f32_32x32x16_f16(a, b, c, 0, 0, 0)

// Split one granule (8 fp32) into fp16 hi (pkrtz, RTZ) + fp16 lo (residual).
__device__ __forceinline__ void cvt_granule(const float4 a, const float4 b,
                                            uint4& hi, uint4& lo) {
    fp16x2 h0 = __builtin_amdgcn_cvt_pkrtz(a.x, a.y);
    fp16x2 h1 = __builtin_amdgcn_cvt_pkrtz(a.z, a.w);
    fp16x2 h2 = __builtin_amdgcn_cvt_pkrtz(b.x, b.y);
    fp16x2 h3 = __builtin_amdgcn_cvt_pkrtz(b.z, b.w);
    fp16x2 l0 = __builtin_amdgcn_cvt_pkrtz(a.x - (float)h0.x, a.y - (float)h0.y);
    fp16x2 l1 = __builtin_amdgcn_cvt_pkrtz(a.z - (float)h1.x, a.w - (float)h1.y);
    fp16x2 l2 = __builtin_amdgcn_cvt_pkrtz(b.x - (float)h2.x, b.y - (float)h2.y);
    fp16x2 l3 = __builtin_amdgcn_cvt_pkrtz(b.z - (float)h3.x, b.w - (float)h3.y);
    hi = make_uint4(__builtin_bit_cast(unsigned, h0), __builtin_bit_cast(unsigned, h1),
                    __builtin_bit_cast(unsigned, h2), __builtin_bit_cast(unsigned, h3));
    lo = make_uint4(__builtin_bit_cast(unsigned, l0), __builtin_bit_cast(unsigned, l1),
                    __builtin_bit_cast(unsigned, l2), __builtin_bit_cast(unsigned, l3));
}

// async global->LDS, 16 B per lane; lds dst must be wave-uniform base.
__device__ __forceinline__ void gl_lds16(const uint4* g, uint4* l) {
    __builtin_amdgcn_global_load_lds(
        (const __attribute__((address_space(1))) void*)g,
        (__attribute__((address_space(3))) void*)l, 16, 0, 0);
}

// ---------------------------------------------------------------------------
// Prologue: esqb[k] = ||e_k||^2 + 1024 (positivity for u64 packing) and
// packed[] init. Shared by both paths.
// ---------------------------------------------------------------------------
__global__ void prologue_kernel(const float* __restrict__ E, float* __restrict__ esqb,
                                unsigned long long* __restrict__ packed) {
    const int t = blockIdx.x * 256 + threadIdx.x;
    if (t < N_ROWS) packed[t] = ~0ull;
    const int gw   = t >> 6;
    const int lane = t & 63;
    const float4 v = ((const float4*)(E + (size_t)gw * D_DIM))[lane];
    float s = v.x * v.x + v.y * v.y + v.z * v.z + v.w * v.w;
#pragma unroll
    for (int off = 32; off; off >>= 1) s += __shfl_down(s, off, 64);
    if (lane == 0) esqb[gw] = s + 1024.0f;
}

// ---------------------------------------------------------------------------
// One-time split to blocked global layout (the exact LDS image):
//  X: granule idx = rb*4096 + dc*512 + gi*128 + r     (rb: 128-row block)
//  E: granule idx = cb*8192 + dc*1024 + gi*256 + c    (cb: 256-code block)
// ---------------------------------------------------------------------------
__global__ __launch_bounds__(256)
void convert_kernel(const float* __restrict__ X, const float* __restrict__ E,
                    uint4* __restrict__ Xh, uint4* __restrict__ Xl,
                    uint4* __restrict__ Eh, uint4* __restrict__ El) {
    const int tid = threadIdx.x;
    if (blockIdx.x < 256) {
        const int rb = blockIdx.x;
#pragma unroll 1
        for (int it = 0; it < 16; ++it) {
            const int idx = it * 256 + tid;
            const int r = idx & 127, gi = (idx >> 7) & 3, dc = idx >> 9;
            const float* p = X + (size_t)(rb * 128 + r) * D_DIM + dc * 32 + gi * 8;
            const float4 a = *(const float4*)p, b = *(const float4*)(p + 4);
            uint4 hi, lo; cvt_granule(a, b, hi, lo);
            Xh[rb * 4096 + idx] = hi; Xl[rb * 4096 + idx] = lo;
        }
    } else {
        const int cb = blockIdx.x - 256;
#pragma unroll 1
        for (int it = 0; it < 32; ++it) {
            const int idx = it * 256 + tid;
            const int c = idx & 255, gi = (idx >> 8) & 3, dc = idx >> 10;
            const float* p = E + (size_t)(cb * 256 + c) * D_DIM + dc * 32 + gi * 8;
            const float4 a = *(const float4*)p, b = *(const float4*)(p + 4);
            uint4 hi, lo; cvt_granule(a, b, hi, lo);
            Eh[cb * 8192 + idx] = hi; El[cb * 8192 + idx] = lo;
        }
    }
}

// ---------------------------------------------------------------------------
// Fast main: pure global_load_lds staging + ds_read_b128 frags + MFMA.
// Block 128 rows x 256-code tiles; wave (wr,wc) owns 64x128 = 2x4 MFMA tiles.
// Per K-step (K=16): 3 passes (xh*eh, xl*eh, xh*el) = 24 MFMA, <=14 b128.
// ---------------------------------------------------------------------------
__global__ __launch_bounds__(256, 2)
void vq_mfma2_kernel(const uint4* __restrict__ Xh, const uint4* __restrict__ Xl,
                     const uint4* __restrict__ Eh, const uint4* __restrict__ El,
                     const float* __restrict__ esqb,
                     unsigned long long* __restrict__ packed) {
    __shared__ uint4 sXh[512], sXl[512], sEh[1024], sEl[1024];   // 48 KB

    const int tid  = threadIdx.x;
    const int lane = tid & 63;
    const int wv   = tid >> 6;
    const int wr   = wv >> 1, wc = wv & 1;
    const int l31  = lane & 31;
    const int lh   = lane >> 5;
    const int wbase = wv << 6;            // wave-uniform LDS granule base
    const int bx   = blockIdx.x;          // row-block
    const int cs0  = blockIdx.y * STRIP;

    const uint4* Xhb = Xh + bx * 4096;
    const uint4* Xlb = Xl + bx * 4096;

    float best[2][16];
    int   bidx[2][16];
#pragma unroll
    for (int ti = 0; ti < 2; ++ti)
#pragma unroll
        for (int r = 0; r < 16; ++r) { best[ti][r] = 3.0e38f; bidx[ti][r] = 0; }

    f32x16 acc[2][4];

#pragma unroll 1
    for (int ct = 0; ct < NCT; ++ct) {
        const uint4* Ehb = Eh + (size_t)(blockIdx.y * NCT + ct) * 8192;
        const uint4* Elb = El + (size_t)(blockIdx.y * NCT + ct) * 8192;

#pragma unroll
        for (int ti = 0; ti < 2; ++ti)
#pragma unroll
            for (int tj = 0; tj < 4; ++tj)
#pragma unroll
                for (int i = 0; i < 16; ++i) acc[ti][tj][i] = 0.0f;

#pragma unroll 1
        for (int dc = 0; dc < NDC; ++dc) {
            __syncthreads();   // prior chunk's ds_reads complete
            const uint4* xs = Xhb + dc * 512;
            const uint4* xl = Xlb + dc * 512;
            const uint4* es = Ehb + dc * 1024;
            const uint4* el = Elb + dc * 1024;
#pragma unroll
            for (int i = 0; i < 2; ++i) gl_lds16(xs + i * 256 + tid, &sXh[i * 256 + wbase]);
#pragma unroll
            for (int i = 0; i < 2; ++i) gl_lds16(xl + i * 256 + tid, &sXl[i * 256 + wbase]);
#pragma unroll
            for (int i = 0; i < 4; ++i) gl_lds16(es + i * 256 + tid, &sEh[i * 256 + wbase]);
#pragma unroll
            for (int i = 0; i < 4; ++i) gl_lds16(el + i * 256 + tid, &sEl[i * 256 + wbase]);
            __syncthreads();   // vmcnt(0) drain: staged data visible

#pragma unroll
            for (int s = 0; s < 2; ++s) {
                const int gi = s * 2 + lh;
                // pass 1: xh * eh
                f16x8 a0[2], b0[4];
#pragma unroll
                for (int ti = 0; ti < 2; ++ti)
                    a0[ti] = __builtin_bit_cast(f16x8, sXh[gi * 128 + wr * 64 + ti * 32 + l31]);
#pragma unroll
                for (int tj = 0; tj < 4; ++tj)
                    b0[tj] = __builtin_bit_cast(f16x8, sEh[gi * 256 + wc * 128 + tj * 32 + l31]);
#pragma unroll
                for (int ti = 0; ti < 2; ++ti)
#pragma unroll
                    for (int tj = 0; tj < 4; ++tj)
                        acc[ti][tj] = MFMA32(a0[ti], b0[tj], acc[ti][tj]);
                // pass 2: xl * eh (reuse b0)
                f16x8 a1[2];
#pragma unroll
                for (int ti = 0; ti < 2; ++ti)
                    a1[ti] = __builtin_bit_cast(f16x8, sXl[gi * 128 + wr * 64 + ti * 32 + l31]);
#pragma unroll
                for (int ti = 0; ti < 2; ++ti)
#pragma unroll
                    for (int tj = 0; tj < 4; ++tj)
                        acc[ti][tj] = MFMA32(a1[ti], b0[tj], acc[ti][tj]);
                // pass 3: xh * el
                f16x8 a2[2], b1[4];
#pragma unroll
                for (int ti = 0; ti < 2; ++ti)
                    a2[ti] = __builtin_bit_cast(f16x8, sXh[gi * 128 + wr * 64 + ti * 32 + l31]);
#pragma unroll
                for (int tj = 0; tj < 4; ++tj)
                    b1[tj] = __builtin_bit_cast(f16x8, sEl[gi * 256 + wc * 128 + tj * 32 + l31]);
#pragma unroll
                for (int ti = 0; ti < 2; ++ti)
#pragma unroll
                    for (int tj = 0; tj < 4; ++tj)
                        acc[ti][tj] = MFMA32(a2[ti], b1[tj], acc[ti][tj]);
            }
        }

        // ---- epilogue: compare-value + running argmin (codes ascending) ----
#pragma unroll
        for (int tj = 0; tj < 4; ++tj) {
            const int code = cs0 + ct * BN + wc * 128 + tj * 32 + l31;
            const float eb = esqb[code];     // esq + 1024
#pragma unroll
            for (int ti = 0; ti < 2; ++ti)
#pragma unroll
                for (int r = 0; r < 16; ++r) {
                    const float dv = fmaf(-2.0f, acc[ti][tj][r], eb);
                    if (dv < best[ti][r]) { best[ti][r] = dv; bidx[ti][r] = code; }
                }
        }
    }

    // ---- butterfly over the 32 code-lanes, then device atomicMin ----
#pragma unroll
    for (int ti = 0; ti < 2; ++ti)
#pragma unroll
        for (int r = 0; r < 16; ++r) {
            float b = best[ti][r]; int bi = bidx[ti][r];
#pragma unroll
            for (int m = 16; m >= 1; m >>= 1) {
                const float ov = __shfl_xor(b, m, 32);
                const int   oi = __shfl_xor(bi, m, 32);
                if (ov < b || (ov == b && oi < bi)) { b = ov; bi = oi; }
            }
            if (l31 == 0) {
                const int row = bx * BM + wr * 64 + ti * 32 + (r & 3) + 8 * (r >> 2) + 4 * lh;
                const unsigned long long p =
                    ((unsigned long long)__float_as_uint(b) << 32) | (unsigned)bi;
                atomicMin(&packed[row], p);
            }
        }
}

// ---------------------------------------------------------------------------
// Fallback (round-4 verified kernel): in-loop split, for small ws_size.
// ---------------------------------------------------------------------------
__global__ __launch_bounds__(256, 2)
void vq_mfma_fallback(const float* __restrict__ X, const float* __restrict__ E,
                      const float* __restrict__ esqb,
                      unsigned long long* __restrict__ packed) {
    __shared__ uint4 fXh[128 * 8], fXl[128 * 8];
    __shared__ uint4 fEh[128 * 8], fEl[128 * 8];
    __shared__ float fEsq[2048];

    const int tid  = threadIdx.x;
    const int lane = tid & 63;
    const int wv   = tid >> 6;
    const int wr   = wv >> 1, wc = wv & 1;
    const int l31  = lane & 31;
    const int lh   = lane >> 5;
    const int row0 = blockIdx.x * 128;
    const int cs0  = blockIdx.y * 2048;

#pragma unroll
    for (int i = 0; i < 8; ++i) fEsq[tid + 256 * i] = esqb[cs0 + tid + 256 * i];

    const int sr = tid >> 3, sg = tid & 7;

    float best[2][16]; int bidx[2][16];
#pragma unroll
    for (int ti = 0; ti < 2; ++ti)
#pragma unroll
        for (int r = 0; r < 16; ++r) { best[ti][r] = 3.0e38f; bidx[ti][r] = 0; }

    f32x16 acc[2][2];

#pragma unroll 1
    for (int ct = 0; ct < 16; ++ct) {
#pragma unroll
        for (int ti = 0; ti < 2; ++ti)
#pragma unroll
            for (int tj = 0; tj < 2; ++tj)
#pragma unroll
                for (int i = 0; i < 16; ++i) acc[ti][tj][i] = 0.0f;

#pragma unroll 1
        for (int dc = 0; dc < 4; ++dc) {
            __syncthreads();
#pragma unroll
            for (int i = 0; i < 4; ++i) {
                const int r = 32 * i + sr;
                const float* p = X + (size_t)(row0 + r) * D_DIM + dc * 64 + sg * 8;
                const float4 a = *(const float4*)p, b = *(const float4*)(p + 4);
                uint4 hi, lo; cvt_granule(a, b, hi, lo);
                const int o = r * 8 + (sg ^ (r & 7));
                fXh[o] = hi; fXl[o] = lo;
            }
#pragma unroll
            for (int i = 0; i < 4; ++i) {
                const int r = 32 * i + sr;
                const float* p = E + (size_t)(cs0 + ct * 128 + r) * D_DIM + dc * 64 + sg * 8;
                const float4 a = *(const float4*)p, b = *(const float4*)(p + 4);
                uint4 hi, lo; cvt_granule(a, b, hi, lo);
                const int o = r * 8 + (sg ^ (r & 7));
                fEh[o] = hi; fEl[o] = lo;
            }
            __syncthreads();

#pragma unroll
            for (int s = 0; s < 4; ++s) {
                const int gi = s * 2 + lh;
                f16x8 axh[2], axl[2], beh[2], bel[2];
#pragma unroll
                for (int ti = 0; ti < 2; ++ti) {
                    const int r = wr * 64 + ti * 32 + l31;
                    const int o = r * 8 + (gi ^ (r & 7));
                    axh[ti] = __builtin_bit_cast(f16x8, fXh[o]);
                    axl[ti] = __builtin_bit_cast(f16x8, fXl[o]);
                }
#pragma unroll
                for (int tj = 0; tj < 2; ++tj) {
                    const int c = wc * 64 + tj * 32 + l31;
                    const int o = c * 8 + (gi ^ (c & 7));
                    beh[tj] = __builtin_bit_cast(f16x8, fEh[o]);
                    bel[tj] = __builtin_bit_cast(f16x8, fEl[o]);
                }
#pragma unroll
                for (int ti = 0; ti < 2; ++ti)
#pragma unroll
                    for (int tj = 0; tj < 2; ++tj) {
                        acc[ti][tj] = MFMA32(axl[ti], beh[tj], acc[ti][tj]);
                        acc[ti][tj] = MFMA32(axh[ti], bel[tj], acc[ti][tj]);
                        acc[ti][tj] = MFMA32(axh[ti], beh[tj], acc[ti][tj]);
                    }
            }
        }

#pragma unroll
        for (int tj = 0; tj < 2; ++tj) {
            const int cloc = ct * 128 + wc * 64 + tj * 32 + l31;
            const float eb = fEsq[cloc];
            const int  code = cs0 + cloc;
#pragma unroll
            for (int ti = 0; ti < 2; ++ti)
#pragma unroll
                for (int r = 0; r < 16; ++r) {
                    const float dv = fmaf(-2.0f, acc[ti][tj][r], eb);
                    if (dv < best[ti][r]) { best[ti][r] = dv; bidx[ti][r] = code; }
                }
        }
    }

#pragma unroll
    for (int ti = 0; ti < 2; ++ti)
#pragma unroll
        for (int r = 0; r < 16; ++r) {
            float b = best[ti][r]; int bi = bidx[ti][r];
#pragma unroll
            for (int m = 16; m >= 1; m >>= 1) {
                const float ov = __shfl_xor(b, m, 32);
                const int   oi = __shfl_xor(bi, m, 32);
                if (ov < b || (ov == b && oi < bi)) { b = ov; bi = oi; }
            }
            if (l31 == 0) {
                const int row = row0 + wr * 64 + ti * 32 + (r & 3) + 8 * (r >> 2) + 4 * lh;
                const unsigned long long p =
                    ((unsigned long long)__float_as_uint(b) << 32) | (unsigned)bi;
                atomicMin(&packed[row], p);
            }
        }
}

// ---------------------------------------------------------------------------
__global__ void finish_kernel(const unsigned long long* __restrict__ packed,
                              int* __restrict__ out) {
    const int i = blockIdx.x * 256 + threadIdx.x;
    out[i] = (int)(unsigned)(packed[i] & 0xffffffffull);
}

// ---------------------------------------------------------------------------
extern "C" void kernel_launch(void* const* d_in, const int* in_sizes, int n_in,
                              void* d_out, int out_size, void* d_ws, size_t ws_size,
                              hipStream_t stream) {
    const float* X = (const float*)d_in[0];    // [32768, 256]
    const float* E = (const float*)d_in[1];    // [8192, 256]
    char* ws = (char*)d_ws;
    float* esqb = (float*)ws;                                        // 32 KB
    unsigned long long* packed = (unsigned long long*)(ws + 32768);  // 256 KB
    int* out = (int*)d_out;

    const size_t base = 294912;                       // 32 KB + 256 KB, 16B-aligned
    const size_t szX  = (size_t)N_ROWS * D_DIM * 2;   // 16 MB per half
    const size_t szE  = (size_t)K_CODES * D_DIM * 2;  // 4 MB per half
    const size_t need = base + 2 * szX + 2 * szE;     // ~40.3 MB + base

    prologue_kernel<<<dim3(2048), dim3(256), 0, stream>>>(E, esqb, packed);

    if (ws_size >= need) {
        uint4* Xh = (uint4*)(ws + base);
        uint4* Xl = (uint4*)(ws + base + szX);
        uint4* Eh = (uint4*)(ws + base + 2 * szX);
        uint4* El = (uint4*)(ws + base + 2 * szX + szE);
        convert_kernel<<<dim3(288), dim3(256), 0, stream>>>(X, E, Xh, Xl, Eh, El);
        vq_mfma2_kernel<<<dim3(N_ROWS / BM, NSTRIP), dim3(256), 0, stream>>>(
            Xh, Xl, Eh, El, esqb, packed);
    } else {
        vq_mfma_fallback<<<dim3(N_ROWS / 128, 4), dim3(256), 0, stream>>>(X, E, esqb, packed);
    }

    finish_kernel<<<dim3(N_ROWS / 256), dim3(256), 0, stream>>>(packed, out);
}